// Round 2
// baseline (64.021 us; speedup 1.0000x reference)
//
#include <hip/hip_runtime.h>
#include <hip/hip_bf16.h>
#include <float.h>
#include <math.h>

#define BB 64
#define T1 33
#define TT 32
#define II 197
#define CC 512
#define TEMP 0.07f

typedef __bf16 bf16x8 __attribute__((ext_vector_type(8)));
typedef float f32x4 __attribute__((ext_vector_type(4)));
typedef unsigned short u16x8 __attribute__((ext_vector_type(8)));

__device__ __forceinline__ unsigned short f32_to_bf16(float f) {
  unsigned int u = __float_as_uint(f);
  unsigned int r = u + 0x7FFFu + ((u >> 16) & 1u);  // RNE
  return (unsigned short)(r >> 16);
}

// ---- workspace layout (bytes) ----
// tl2: [8 xc8][16 kk][16 fa][64 lane][8] bf16  A-frags for 16x16x32:
//      row = fa*16 + (lane&15) = x_local*32 + t ; k = kk*32 + (lane>>4)*8 + j
// ve2: [64 y][16 kk][16 fb][64 lane][8] bf16  B-frags: col i = fb*16 + (lane&15)
// tti: [64 x][64 y] f32 ; cnt: completion counter
#define TL_OFF  0
#define VE_OFF  2097152
#define TTI_OFF (2097152 + 16777216)   // 18874368
#define CNT_OFF (TTI_OFF + 16384)

// grid (64, 8): hz 0..3 = video c-chunks, hz 4..7 = text c-chunks.
__global__ __launch_bounds__(256) void norm_all_kernel(const float* __restrict__ text,
                                                       const float* __restrict__ video,
                                                       unsigned short* __restrict__ tl2,
                                                       unsigned short* __restrict__ ve2,
                                                       unsigned int* __restrict__ gcnt) {
  int b = blockIdx.x, hz = blockIdx.y, tid = threadIdx.x;
  if (b == 0 && hz == 0 && tid == 0) *gcnt = 0;  // visible to sim via kernel boundary
  bool isV = hz < 4;
  int h2 = isV ? hz : hz - 4;
  const float* src = isV ? (video + (size_t)b * II * CC) : (text + (size_t)b * T1 * CC);
  int n = isV ? II : T1;

  __shared__ float red[8][128];
  __shared__ float rn[128];
  __shared__ unsigned short tile[2][16][136];

  // pass 1: sum of squares over axis=1, coalesced row reads
  {
    int c4 = tid & 31, rg = tid >> 5;
    const float* p = src + h2 * 128 + c4 * 4;
    float4 s = {0.f, 0.f, 0.f, 0.f};
    for (int i = rg; i < n; i += 8) {
      float4 v = *(const float4*)(p + (size_t)i * CC);
      s.x += v.x * v.x; s.y += v.y * v.y; s.z += v.z * v.z; s.w += v.w * v.w;
    }
    *(float4*)&red[rg][c4 * 4] = s;
  }
  __syncthreads();
  if (tid < 128) {
    float s = 0.f;
#pragma unroll
    for (int g = 0; g < 8; ++g) s += red[g][tid];
    rn[tid] = 1.0f / sqrtf(s);
  }
  __syncthreads();

  // pass 2: normalize + bf16 + frag-layout transpose via ping-pong LDS
  int nfb = isV ? 16 : 2;
  int row_l = tid >> 4, c8 = tid & 15;
  int q = tid >> 6, lane = tid & 63;
  int lim = isV ? II : 32;
  for (int fb = 0; fb < nfb; ++fb) {
    int pp = fb & 1;
    int i = fb * 16 + row_l;
    int isrc = isV ? i : (1 + i);
    float4 v0 = {0.f, 0.f, 0.f, 0.f}, v1 = {0.f, 0.f, 0.f, 0.f};
    if (i < lim) {
      const float* p = src + (size_t)isrc * CC + h2 * 128 + c8 * 8;
      v0 = *(const float4*)p;
      v1 = *(const float4*)(p + 4);
    }
    float4 r0 = *(const float4*)&rn[c8 * 8];
    float4 r1 = *(const float4*)&rn[c8 * 8 + 4];
    u16x8 o;
    o[0] = f32_to_bf16(v0.x * r0.x); o[1] = f32_to_bf16(v0.y * r0.y);
    o[2] = f32_to_bf16(v0.z * r0.z); o[3] = f32_to_bf16(v0.w * r0.w);
    o[4] = f32_to_bf16(v1.x * r1.x); o[5] = f32_to_bf16(v1.y * r1.y);
    o[6] = f32_to_bf16(v1.z * r1.z); o[7] = f32_to_bf16(v1.w * r1.w);
    *(u16x8*)&tile[pp][row_l][c8 * 8] = o;
    __syncthreads();

    int kgl = q * 4 + (lane >> 4), il = lane & 15;
    u16x8 t8 = *(const u16x8*)&tile[pp][il][kgl * 8];
    if (isV) {
      *(u16x8*)(ve2 + ((((size_t)b * 16 + h2 * 4 + q) * 16 + fb) * 64 + lane) * 8) = t8;
    } else {
      int xc = b >> 3, fa = (b & 7) * 2 + fb;
      *(u16x8*)(tl2 + ((((size_t)xc * 16 + h2 * 4 + q) * 16 + fa) * 64 + lane) * 8) = t8;
    }
  }
}

#define BITC(u) __builtin_bit_cast(bf16x8, u)

typedef __attribute__((address_space(3))) unsigned int lds_u32;
typedef __attribute__((address_space(1))) const unsigned int glb_u32;
__device__ __forceinline__ void gl16(const unsigned short* g, unsigned short* l) {
  __builtin_amdgcn_global_load_lds((glb_u32*)(const void*)g, (lds_u32*)(void*)l, 16, 0, 0);
}

// 1024 blocks x 512 threads, 2 blocks/CU. Block (xcb, y): 128 rows x 256 cols,
// K=512 as 16 kk-phases, ring-3 LDS slots + counted vmcnt(3), wn==3 trimmed to
// frag 12, setprio around MFMA. NEW: loss fused via last-block finalize —
// tti stored with device-scope atomicExch (coherent across XCDs), completion
// counter, last block computes the softmax loss (removes loss_kernel + edge).
__global__ __launch_bounds__(512, 4) void sim_kernel(const unsigned short* __restrict__ tl2,
                                                     const unsigned short* __restrict__ ve2,
                                                     const int* __restrict__ mask,
                                                     float* __restrict__ tti,
                                                     unsigned int* __restrict__ gcnt,
                                                     float* __restrict__ out) {
  int L = blockIdx.x;
  int xcd = L & 7;
  int idx = L >> 3;              // 0..127
  int y = xcd * 8 + (idx & 7);   // each XCD owns 8 consecutive y's
  int xcb = idx >> 3;            // 0..15 : 4 batch-x per block

  int tid = threadIdx.x;
  int w = tid >> 6, lane = tid & 63;
  int wm = w >> 2;               // 0..1 : rows wm*64..+64 (4 frags)
  int wn = w & 3;                // 0..3 : cols wn*64..+64 (4 frags)

  __shared__ unsigned short As[3 * 8 * 512];   // [slot][fa][lane*8] 24KB
  __shared__ unsigned short Bs[3 * 16 * 512];  // [slot][fb][lane*8] 48KB
  __shared__ float smax[4 * 128];              // [wn][row] 2KB
  __shared__ float lxs[64];
  __shared__ int islast;

  // A chunk for this block: 8 contiguous fa frags within the xc8 group
  const unsigned short* Abase =
      tl2 + ((size_t)(xcb >> 1) * 16 * 16 + (xcb & 1) * 8) * 512;  // +kk*16*512
  const unsigned short* Bbase = ve2 + (size_t)y * 16 * 8192;

#define STG_A(k_) do {                                                        \
    const unsigned short* s_ = Abase + (size_t)(k_) * 8192 + w * 512 + lane * 8; \
    unsigned short* d_ = (unsigned short*)As + ((((k_) % 3)) * 8 + w) * 512;  \
    gl16(s_, d_);                                                             \
  } while (0)
#define STG_B(k_) do {                                                        \
    const unsigned short* s_ = Bbase + (size_t)(k_) * 8192 + (w * 2) * 512 + lane * 8; \
    unsigned short* d_ = (unsigned short*)Bs + ((((k_) % 3)) * 16 + w * 2) * 512; \
    gl16(s_, d_); gl16(s_ + 512, d_ + 512);                                   \
  } while (0)

  f32x4 acc[4][4] = {};

  // prologue: slots 0 and 1 staged; wait for slot 0 (3 newest ops may fly)
  STG_A(0); STG_B(0);
  STG_A(1); STG_B(1);
  asm volatile("s_waitcnt vmcnt(3)" ::: "memory");
  __builtin_amdgcn_s_barrier();

#pragma unroll
  for (int k = 0; k < 16; ++k) {
    if (k < 14) { STG_A(k + 2); STG_B(k + 2); }  // keep 2 slots in flight

    int slot = k % 3;  // compile-time (full unroll)
    u16x8 a[4], b[4];
#pragma unroll
    for (int ma = 0; ma < 4; ++ma)
      a[ma] = *(const u16x8*)&As[(slot * 8 + wm * 4 + ma) * 512 + lane * 8];

    if (wn == 3) {
      // cols 192..255: only frag 12 (cols 192..207) can contain i<197
      b[0] = *(const u16x8*)&Bs[(slot * 16 + 12) * 512 + lane * 8];
      __builtin_amdgcn_s_setprio(1);
#pragma unroll
      for (int ma = 0; ma < 4; ++ma)
        acc[ma][0] = __builtin_amdgcn_mfma_f32_16x16x32_bf16(
            BITC(a[ma]), BITC(b[0]), acc[ma][0], 0, 0, 0);
      __builtin_amdgcn_s_setprio(0);
    } else {
#pragma unroll
      for (int nb = 0; nb < 4; ++nb)
        b[nb] = *(const u16x8*)&Bs[(slot * 16 + wn * 4 + nb) * 512 + lane * 8];
      __builtin_amdgcn_s_setprio(1);
#pragma unroll
      for (int ma = 0; ma < 4; ++ma)
#pragma unroll
        for (int nb = 0; nb < 4; ++nb)
          acc[ma][nb] = __builtin_amdgcn_mfma_f32_16x16x32_bf16(
              BITC(a[ma]), BITC(b[nb]), acc[ma][nb], 0, 0, 0);
      __builtin_amdgcn_s_setprio(0);
    }

    if (k < 15) {
      // need slot k+1 landed; slot k+2's 3 ops/wave may stay in flight
      if (k < 14) asm volatile("s_waitcnt vmcnt(3)" ::: "memory");
      else        asm volatile("s_waitcnt vmcnt(0)" ::: "memory");
      __builtin_amdgcn_s_barrier();
    }
  }
#undef STG_A
#undef STG_B

  // ---- fused epilogue: max over i (i<197), masked mean over t -> tti ----
  int col = lane & 15, gq = lane >> 4;
  bool valid[4];
#pragma unroll
  for (int nb = 0; nb < 4; ++nb) valid[nb] = (wn * 64 + nb * 16 + col) < II;

  float mx[4][4];
#pragma unroll
  for (int ma = 0; ma < 4; ++ma)
#pragma unroll
    for (int reg = 0; reg < 4; ++reg) {
      float m = -FLT_MAX;
#pragma unroll
      for (int nb = 0; nb < 4; ++nb)
        if (valid[nb]) m = fmaxf(m, acc[ma][nb][reg]);
      mx[ma][reg] = m;
    }
#pragma unroll
  for (int st = 1; st <= 8; st <<= 1)
#pragma unroll
    for (int ma = 0; ma < 4; ++ma)
#pragma unroll
      for (int reg = 0; reg < 4; ++reg)
        mx[ma][reg] = fmaxf(mx[ma][reg], __shfl_xor(mx[ma][reg], st));

  if (col == 0) {
#pragma unroll
    for (int ma = 0; ma < 4; ++ma)
#pragma unroll
      for (int reg = 0; reg < 4; ++reg)
        smax[wn * 128 + wm * 64 + ma * 16 + gq * 4 + reg] = mx[ma][reg];
  }
  __syncthreads();

  if (tid < 128) {
    int r = tid;                       // row = x_local*32 + t
    float m = fmaxf(fmaxf(smax[r], smax[128 + r]),
                    fmaxf(smax[256 + r], smax[384 + r]));
    int x = xcb * 4 + (r >> 5), tt = r & 31;
    int mk = mask[x * T1 + 1 + tt];
    float num = mk ? m * TEMP : 0.f;
    float cntm = mk ? 1.f : 0.f;
#pragma unroll
    for (int st = 1; st < 32; st <<= 1) {
      num += __shfl_xor(num, st);
      cntm += __shfl_xor(cntm, st);
    }
    // device-scope atomic store -> coherent point, visible cross-XCD
    if (tt == 0) atomicExch(&tti[x * 64 + y], num / fmaxf(cntm, 1e-6f));
  }

  // ---- completion counter; last block computes the loss ----
  __syncthreads();  // implicit s_waitcnt vmcnt(0): atomicExch drained/visible
  if (tid == 0) islast = (atomicAdd(gcnt, 1u) == 1023u) ? 1 : 0;
  __syncthreads();
  if (!islast) return;

  __threadfence();  // compiler/mem barrier before reading others' tti
  {
    int x = tid >> 3, q = tid & 7;  // 64 rows x 8 lanes, 8 y's each
    float4 v0 = *(const float4*)&tti[x * 64 + q * 8];
    float4 v1 = *(const float4*)&tti[x * 64 + q * 8 + 4];
    float den = expf(v0.x) + expf(v0.y) + expf(v0.z) + expf(v0.w) +
                expf(v1.x) + expf(v1.y) + expf(v1.z) + expf(v1.w);
#pragma unroll
    for (int st = 1; st <= 4; st <<= 1) den += __shfl_xor(den, st);
    if (q == 0) lxs[x] = -logf(expf(tti[x * 65]) / den + 1e-20f);
  }
  __syncthreads();
  if (tid < 64) {
    float lx = lxs[tid];
#pragma unroll
    for (int s = 1; s < 64; s <<= 1) lx += __shfl_xor(lx, s);
    if (tid == 0) out[0] = lx * (1.0f / 64.0f);
  }
}

extern "C" void kernel_launch(void* const* d_in, const int* in_sizes, int n_in,
                              void* d_out, int out_size, void* d_ws, size_t ws_size,
                              hipStream_t stream) {
  const float* text = (const float*)d_in[0];   // [64][33][512] f32
  const float* video = (const float*)d_in[1];  // [64][197][512] f32
  const int* mask = (const int*)d_in[2];       // [64][33] i32
  float* out = (float*)d_out;

  char* ws = (char*)d_ws;
  unsigned short* tl2 = (unsigned short*)(ws + TL_OFF);
  unsigned short* ve2 = (unsigned short*)(ws + VE_OFF);
  float* tti = (float*)(ws + TTI_OFF);
  unsigned int* gcnt = (unsigned int*)(ws + CNT_OFF);

  hipLaunchKernelGGL(norm_all_kernel, dim3(BB, 8), dim3(256), 0, stream, text, video, tl2, ve2, gcnt);
  hipLaunchKernelGGL(sim_kernel, dim3(1024), dim3(512), 0, stream, tl2, ve2, mask, tti, gcnt, out);
}

// Round 3
// 51.589 us; speedup vs baseline: 1.2410x; 1.2410x over previous
//
#include <hip/hip_runtime.h>
#include <hip/hip_bf16.h>
#include <float.h>
#include <math.h>

#define BB 64
#define T1 33
#define TT 32
#define II 197
#define CC 512
#define TEMP 0.07f

typedef float f32x4 __attribute__((ext_vector_type(4)));
typedef unsigned int u32x4 __attribute__((ext_vector_type(4)));
typedef unsigned int u32x2 __attribute__((ext_vector_type(2)));

// ---- workspace layout (bytes) ----
// tl8: [8 xc8][16 kk][8 pa][64 lane][16] fp8  A frag-PAIRS for 16x16x32 fp8:
//      bytes 0-7 = frag 2*pa (row = 2*pa*16+(lane&15)), 8-15 = frag 2*pa+1;
//      within 8 bytes: k = kk*32 + (lane>>4)*8 + j
// ve8: [64 y][16 kk][8 pb][64 lane][16] fp8  B frag-pairs, col i = frag*16+(lane&15)
// tti: [64 x][64 y] f32
#define TL_OFF  0
#define VE_OFF  (1 << 20)                  // 1 MB
#define TTI_OFF ((1 << 20) + (8 << 20))    // 9 MB

// grid (64, 8): hz 0..3 = video c-chunks, hz 4..7 = text c-chunks.
__global__ __launch_bounds__(256) void norm_all_kernel(const float* __restrict__ text,
                                                       const float* __restrict__ video,
                                                       unsigned char* __restrict__ tl8,
                                                       unsigned char* __restrict__ ve8) {
  int b = blockIdx.x, hz = blockIdx.y, tid = threadIdx.x;
  bool isV = hz < 4;
  int h2 = isV ? hz : hz - 4;
  const float* src = isV ? (video + (size_t)b * II * CC) : (text + (size_t)b * T1 * CC);
  int n = isV ? II : T1;

  __shared__ float red[8][128];
  __shared__ float rn[128];

  // pass 1: sum of squares over axis=1, coalesced row reads
  {
    int c4 = tid & 31, rg = tid >> 5;
    const float* p = src + h2 * 128 + c4 * 4;
    float4 s = {0.f, 0.f, 0.f, 0.f};
    for (int i = rg; i < n; i += 8) {
      float4 v = *(const float4*)(p + (size_t)i * CC);
      s.x += v.x * v.x; s.y += v.y * v.y; s.z += v.z * v.z; s.w += v.w * v.w;
    }
    *(float4*)&red[rg][c4 * 4] = s;
  }
  __syncthreads();
  if (tid < 128) {
    float s = 0.f;
#pragma unroll
    for (int g = 0; g < 8; ++g) s += red[g][tid];
    rn[tid] = 1.0f / sqrtf(s);
  }
  __syncthreads();

  // pass 2: each thread builds one 16-B frag-pair slice directly from global
  // (L2-warm re-read), normalizes, converts to fp8 e4m3, coalesced 16-B store.
  int lane = tid & 63;
  int q = tid >> 6;                     // kk within chunk = h2*4 + q
  int kgl = q * 4 + ((lane >> 4) & 3);  // 8-col group within the 128-chunk
  int il = tid & 15;                    // row within frag
  float4 r0 = *(const float4*)&rn[kgl * 8];
  float4 r1 = *(const float4*)&rn[kgl * 8 + 4];
  int nfb2 = isV ? 8 : 1;
  int lim = isV ? II : 32;
  for (int fb2 = 0; fb2 < nfb2; ++fb2) {
    unsigned int wd[4];
#pragma unroll
    for (int hf = 0; hf < 2; ++hf) {
      int i = fb2 * 32 + hf * 16 + il;
      int isrc = isV ? i : (1 + i);
      float4 u0 = {0.f, 0.f, 0.f, 0.f}, u1 = {0.f, 0.f, 0.f, 0.f};
      if (i < lim) {
        const float* p = src + (size_t)isrc * CC + h2 * 128 + kgl * 8;
        u0 = *(const float4*)p;
        u1 = *(const float4*)(p + 4);
      }
      int wa = __builtin_amdgcn_cvt_pk_fp8_f32(u0.x * r0.x, u0.y * r0.y, 0, 0);
      wa = __builtin_amdgcn_cvt_pk_fp8_f32(u0.z * r0.z, u0.w * r0.w, wa, 1);
      int wb = __builtin_amdgcn_cvt_pk_fp8_f32(u1.x * r1.x, u1.y * r1.y, 0, 0);
      wb = __builtin_amdgcn_cvt_pk_fp8_f32(u1.z * r1.z, u1.w * r1.w, wb, 1);
      wd[hf * 2] = (unsigned int)wa;
      wd[hf * 2 + 1] = (unsigned int)wb;
    }
    u32x4 o = {wd[0], wd[1], wd[2], wd[3]};
    unsigned char* dst;
    if (isV) {
      dst = ve8 + ((((size_t)b * 16 + h2 * 4 + q) * 8 + fb2) * 1024) + lane * 16;
    } else {
      dst = tl8 + ((((size_t)(b >> 3) * 16 + h2 * 4 + q) * 8 + (b & 7)) * 1024) + lane * 16;
    }
    *(u32x4*)dst = o;
  }
}

typedef __attribute__((address_space(3))) unsigned int lds_u32;
typedef __attribute__((address_space(1))) const unsigned int glb_u32;
__device__ __forceinline__ void gl16(const unsigned char* g, unsigned char* l) {
  __builtin_amdgcn_global_load_lds((glb_u32*)(const void*)g, (lds_u32*)(void*)l, 16, 0, 0);
}

__device__ __forceinline__ long long half64(u32x4 v, int h) {
  u32x2 r = {v[h * 2], v[h * 2 + 1]};
  return __builtin_bit_cast(long long, r);
}

// 1024 blocks x 512 threads, 2 blocks/CU (74 KB LDS). Block (xcb, y):
// 128 rows x 256 cols, K=512 as 8 BK=64 phases (fp8 halves operand bytes ->
// frag-pairs per ds_read_b128, half the LDS-read work, half the phases).
// Ring-3 slots, uniform 3 gl16/wave/phase, counted vmcnt(3), wn==3 trimmed
// to frag 12, setprio around MFMA.
__global__ __launch_bounds__(512, 4) void sim_kernel(const unsigned char* __restrict__ tl8,
                                                     const unsigned char* __restrict__ ve8,
                                                     const int* __restrict__ mask,
                                                     float* __restrict__ tti) {
  int L = blockIdx.x;
  int xcd = L & 7;
  int idx = L >> 3;              // 0..127
  int y = xcd * 8 + (idx & 7);   // each XCD owns 8 consecutive y's
  int xcb = idx >> 3;            // 0..15 : 4 batch-x per block

  int tid = threadIdx.x;
  int w = tid >> 6, lane = tid & 63;
  int wm = w >> 2;               // 0..1 : rows wm*64..+64 (4 frags)
  int wn = w & 3;                // 0..3 : cols wn*64..+64 (4 frags)

  __shared__ __attribute__((aligned(16))) unsigned char As[3][8][1024];   // [slot][kk2*4+fa2p] 24KB
  __shared__ __attribute__((aligned(16))) unsigned char Bs[3][16][1024];  // [slot][kk2*8+fb2p] 48KB
  __shared__ float smax[4 * 128];                                         // 2KB

  // A pairs for this block: 4 contiguous pairs within the xc8 group
  const unsigned char* Abase =
      tl8 + ((size_t)(xcb >> 1) * 16 * 8 + (xcb & 1) * 4) * 1024;  // + kk*8*1024
  const unsigned char* Bbase = ve8 + (size_t)y * 16 * 8 * 1024;

  // per phase: A = 2kk x 4 pairs (8 KB), B = 2kk x 8 pairs (16 KB) = 24 gl16,
  // 3 per wave (uniform -> clean per-wave vmcnt).
#define STG(p_) do {                                                          \
    int s_ = (p_) % 3;                                                        \
    _Pragma("unroll")                                                         \
    for (int r_ = 0; r_ < 3; ++r_) {                                          \
      int j_ = w * 3 + r_;                                                    \
      if (j_ < 8) {                                                           \
        int kk2_ = j_ >> 2, fa2_ = j_ & 3;                                    \
        const unsigned char* g_ =                                             \
            Abase + ((size_t)(2 * (p_) + kk2_) * 8 + fa2_) * 1024 + lane * 16; \
        gl16(g_, &As[s_][kk2_ * 4 + fa2_][lane * 16]);                        \
      } else {                                                                \
        int jb_ = j_ - 8, kk2_ = jb_ >> 3, fb2_ = jb_ & 7;                    \
        const unsigned char* g_ =                                             \
            Bbase + ((size_t)(2 * (p_) + kk2_) * 8 + fb2_) * 1024 + lane * 16; \
        gl16(g_, &Bs[s_][kk2_ * 8 + fb2_][lane * 16]);                        \
      }                                                                       \
    }                                                                         \
  } while (0)

  f32x4 acc[4][4] = {};

  // prologue: slots 0 and 1 staged (6 ops/wave); wait for slot 0 (allow 3)
  STG(0); STG(1);
  asm volatile("s_waitcnt vmcnt(3)" ::: "memory");
  __builtin_amdgcn_s_barrier();

#pragma unroll
  for (int p = 0; p < 8; ++p) {
    if (p < 6) STG(p + 2);  // keep 2 slots in flight

    int slot = p % 3;  // compile-time (full unroll)
    u32x4 av[2][2];
#pragma unroll
    for (int kk2 = 0; kk2 < 2; ++kk2)
#pragma unroll
      for (int pp = 0; pp < 2; ++pp)
        av[kk2][pp] = *(const u32x4*)&As[slot][kk2 * 4 + wm * 2 + pp][lane * 16];

    if (wn == 3) {
      // cols 192..255: only frag 12 (pair 6, even half) can contain i<197
      long long bl[2];
#pragma unroll
      for (int kk2 = 0; kk2 < 2; ++kk2) {
        u32x4 t = *(const u32x4*)&Bs[slot][kk2 * 8 + 6][lane * 16];
        bl[kk2] = half64(t, 0);
      }
      __builtin_amdgcn_s_setprio(1);
#pragma unroll
      for (int kk2 = 0; kk2 < 2; ++kk2)
#pragma unroll
        for (int ma = 0; ma < 4; ++ma)
          acc[ma][0] = __builtin_amdgcn_mfma_f32_16x16x32_fp8_fp8(
              half64(av[kk2][ma >> 1], ma & 1), bl[kk2], acc[ma][0], 0, 0, 0);
      __builtin_amdgcn_s_setprio(0);
    } else {
      u32x4 bv[2][2];
#pragma unroll
      for (int kk2 = 0; kk2 < 2; ++kk2)
#pragma unroll
        for (int pp = 0; pp < 2; ++pp)
          bv[kk2][pp] = *(const u32x4*)&Bs[slot][kk2 * 8 + wn * 2 + pp][lane * 16];
      __builtin_amdgcn_s_setprio(1);
#pragma unroll
      for (int kk2 = 0; kk2 < 2; ++kk2)
#pragma unroll
        for (int ma = 0; ma < 4; ++ma)
#pragma unroll
          for (int nb = 0; nb < 4; ++nb)
            acc[ma][nb] = __builtin_amdgcn_mfma_f32_16x16x32_fp8_fp8(
                half64(av[kk2][ma >> 1], ma & 1), half64(bv[kk2][nb >> 1], nb & 1),
                acc[ma][nb], 0, 0, 0);
      __builtin_amdgcn_s_setprio(0);
    }

    if (p < 7) {
      // need slot p+1 landed; slot p+2's 3 ops/wave may stay in flight
      if (p < 6) asm volatile("s_waitcnt vmcnt(3)" ::: "memory");
      else       asm volatile("s_waitcnt vmcnt(0)" ::: "memory");
      __builtin_amdgcn_s_barrier();
    }
  }
#undef STG

  // ---- fused epilogue: max over i (i<197), masked mean over t -> tti ----
  int col = lane & 15, gq = lane >> 4;
  bool valid[4];
#pragma unroll
  for (int nb = 0; nb < 4; ++nb) valid[nb] = (wn * 64 + nb * 16 + col) < II;

  float mx[4][4];
#pragma unroll
  for (int ma = 0; ma < 4; ++ma)
#pragma unroll
    for (int reg = 0; reg < 4; ++reg) {
      float m = -FLT_MAX;
#pragma unroll
      for (int nb = 0; nb < 4; ++nb)
        if (valid[nb]) m = fmaxf(m, acc[ma][nb][reg]);
      mx[ma][reg] = m;
    }
#pragma unroll
  for (int st = 1; st <= 8; st <<= 1)
#pragma unroll
    for (int ma = 0; ma < 4; ++ma)
#pragma unroll
      for (int reg = 0; reg < 4; ++reg)
        mx[ma][reg] = fmaxf(mx[ma][reg], __shfl_xor(mx[ma][reg], st));

  if (col == 0) {
#pragma unroll
    for (int ma = 0; ma < 4; ++ma)
#pragma unroll
      for (int reg = 0; reg < 4; ++reg)
        smax[wn * 128 + wm * 64 + ma * 16 + gq * 4 + reg] = mx[ma][reg];
  }
  __syncthreads();

  if (tid < 128) {
    int r = tid;                       // row = x_local*32 + t
    float m = fmaxf(fmaxf(smax[r], smax[128 + r]),
                    fmaxf(smax[256 + r], smax[384 + r]));
    int x = xcb * 4 + (r >> 5), tt = r & 31;
    int mk = mask[x * T1 + 1 + tt];
    float num = mk ? m * TEMP : 0.f;
    float cnt = mk ? 1.f : 0.f;
#pragma unroll
    for (int st = 1; st < 32; st <<= 1) {
      num += __shfl_xor(num, st);
      cnt += __shfl_xor(cnt, st);
    }
    if (tt == 0) tti[x * 64 + y] = num / fmaxf(cnt, 1e-6f);
  }
}

// 1 block x 1024 threads: 16 threads per row x, each sums 4 y's.
__global__ void loss_kernel(const float* __restrict__ tti, float* __restrict__ out) {
  __shared__ float lxs[64];
  int tid = threadIdx.x;
  int x = tid >> 4, q = tid & 15;
  float4 v = *(const float4*)&tti[x * 64 + q * 4];
  float den = expf(v.x) + expf(v.y) + expf(v.z) + expf(v.w);
#pragma unroll
  for (int st = 1; st < 16; st <<= 1) den += __shfl_xor(den, st);
  if (q == 0) {
    float pos = expf(tti[x * 64 + x]);
    lxs[x] = -logf(pos / den + 1e-20f);
  }
  __syncthreads();
  if (tid < 64) {
    float lx = lxs[tid];
#pragma unroll
    for (int s = 1; s < 64; s <<= 1) lx += __shfl_xor(lx, s);
    if (tid == 0) out[0] = lx * (1.0f / 64.0f);
  }
}

extern "C" void kernel_launch(void* const* d_in, const int* in_sizes, int n_in,
                              void* d_out, int out_size, void* d_ws, size_t ws_size,
                              hipStream_t stream) {
  const float* text = (const float*)d_in[0];   // [64][33][512] f32
  const float* video = (const float*)d_in[1];  // [64][197][512] f32
  const int* mask = (const int*)d_in[2];       // [64][33] i32
  float* out = (float*)d_out;

  char* ws = (char*)d_ws;
  unsigned char* tl8 = (unsigned char*)(ws + TL_OFF);
  unsigned char* ve8 = (unsigned char*)(ws + VE_OFF);
  float* tti = (float*)(ws + TTI_OFF);

  hipLaunchKernelGGL(norm_all_kernel, dim3(BB, 8), dim3(256), 0, stream, text, video, tl8, ve8);
  hipLaunchKernelGGL(sim_kernel, dim3(1024), dim3(512), 0, stream, tl8, ve8, mask, tti);
  hipLaunchKernelGGL(loss_kernel, dim3(1), dim3(1024), 0, stream, tti, out);
}

// Round 4
// 50.605 us; speedup vs baseline: 1.2651x; 1.0194x over previous
//
#include <hip/hip_runtime.h>
#include <hip/hip_bf16.h>
#include <float.h>
#include <math.h>

#define BB 64
#define T1 33
#define TT 32
#define II 197
#define CC 512
#define TEMP 0.07f

typedef float f32x4 __attribute__((ext_vector_type(4)));
typedef int i32x4 __attribute__((ext_vector_type(4)));
typedef int i32x8 __attribute__((ext_vector_type(8)));

// ---- workspace layout (bytes) ----
// Frag records for mfma_scale_f32_16x16x128_f8f6f4 (fp8): per frag per kstep,
// 2048 B = [half h 0..1][lane 0..63][16 B]; element (row/col = lane&15,
// k = ks*128 + (lane>>4)*32 + h*16 + j).
// tl8: [xc8 8][ks 4][fa 16] records  (1 MB)   A: text rows r=fa*16+(lane&15)
// ve8: [y 64][ks 4][fb 16] records  (8 MB)   B: cols  i=fb*16+(lane&15); fb<=12 written
// tti: [64 x][64 y] f32
#define TL_OFF  0
#define VE_OFF  (1 << 20)                  // 1 MB
#define TTI_OFF ((1 << 20) + (8 << 20))    // 9 MB
#define KS_STRIDE   32768                  // 16 frags * 2048
#define GRP_STRIDE  131072                 // 4 ks * KS_STRIDE

// grid (64, 8): hz 0..3 = video c-chunks (= ksteps), hz 4..7 = text c-chunks.
__global__ __launch_bounds__(256) void norm_all_kernel(const float* __restrict__ text,
                                                       const float* __restrict__ video,
                                                       unsigned char* __restrict__ tl8,
                                                       unsigned char* __restrict__ ve8) {
  int b = blockIdx.x, hz = blockIdx.y, tid = threadIdx.x;
  bool isV = hz < 4;
  int h2 = isV ? hz : hz - 4;                  // kstep
  const float* src = isV ? (video + (size_t)b * II * CC) : (text + (size_t)b * T1 * CC);
  int n = isV ? II : T1;

  __shared__ float red[8][128];
  __shared__ float rn[128];

  // pass 1: sum of squares over axis=1 (rows), coalesced row reads
  {
    int c4 = tid & 31, rg = tid >> 5;
    const float* p = src + h2 * 128 + c4 * 4;
    float4 s = {0.f, 0.f, 0.f, 0.f};
    for (int i = rg; i < n; i += 8) {
      float4 v = *(const float4*)(p + (size_t)i * CC);
      s.x += v.x * v.x; s.y += v.y * v.y; s.z += v.z * v.z; s.w += v.w * v.w;
    }
    *(float4*)&red[rg][c4 * 4] = s;
  }
  __syncthreads();
  if (tid < 128) {
    float s = 0.f;
#pragma unroll
    for (int g = 0; g < 8; ++g) s += red[g][tid];
    rn[tid] = 1.0f / sqrtf(s);
  }
  __syncthreads();

  // pass 2: build 16-B record slices directly from global (L2-warm), fp8 e4m3.
  // slice (frag f, half h, lane l): row/col = f*16+(l&15),
  // channels = h2*128 + (l>>4)*32 + h*16 + {0..15}
  if (isV) {
    for (int S = tid; S < 13 * 128; S += 256) {
      int fb = S >> 7, h = (S >> 6) & 1, lane = S & 63;
      int i = fb * 16 + (lane & 15);
      int kloc = ((lane >> 4) & 3) * 32 + h * 16;
      float4 u[4] = {};
      if (i < II) {
        const float* p = src + (size_t)i * CC + h2 * 128 + kloc;
#pragma unroll
        for (int q = 0; q < 4; ++q) u[q] = *(const float4*)(p + q * 4);
      }
      unsigned int wd[4];
#pragma unroll
      for (int q = 0; q < 4; ++q) {
        float4 r = *(const float4*)&rn[kloc + q * 4];
        int wv = __builtin_amdgcn_cvt_pk_fp8_f32(u[q].x * r.x, u[q].y * r.y, 0, 0);
        wv = __builtin_amdgcn_cvt_pk_fp8_f32(u[q].z * r.z, u[q].w * r.w, wv, 1);
        wd[q] = (unsigned int)wv;
      }
      unsigned char* dst = ve8 + (size_t)b * GRP_STRIDE + h2 * KS_STRIDE +
                           fb * 2048 + h * 1024 + lane * 16;
      *(uint4*)dst = make_uint4(wd[0], wd[1], wd[2], wd[3]);
    }
  } else {
    // 2 fa_local x 2 h x 64 lane = 256 slices, one per thread
    int fa_local = tid >> 7, h = (tid >> 6) & 1, lane = tid & 63;
    int t = fa_local * 16 + (lane & 15);          // 0..31
    int kloc = ((lane >> 4) & 3) * 32 + h * 16;
    const float* p = src + (size_t)(1 + t) * CC + h2 * 128 + kloc;
    unsigned int wd[4];
#pragma unroll
    for (int q = 0; q < 4; ++q) {
      float4 u = *(const float4*)(p + q * 4);
      float4 r = *(const float4*)&rn[kloc + q * 4];
      int wv = __builtin_amdgcn_cvt_pk_fp8_f32(u.x * r.x, u.y * r.y, 0, 0);
      wv = __builtin_amdgcn_cvt_pk_fp8_f32(u.z * r.z, u.w * r.w, wv, 1);
      wd[q] = (unsigned int)wv;
    }
    int fa = (b & 7) * 2 + fa_local;
    unsigned char* dst = tl8 + (size_t)(b >> 3) * GRP_STRIDE + h2 * KS_STRIDE +
                         fa * 2048 + h * 1024 + lane * 16;
    *(uint4*)dst = make_uint4(wd[0], wd[1], wd[2], wd[3]);
  }
}

typedef __attribute__((address_space(3))) unsigned int lds_u32;
typedef __attribute__((address_space(1))) const unsigned int glb_u32;
__device__ __forceinline__ void gl16(const unsigned char* g, unsigned char* l) {
  __builtin_amdgcn_global_load_lds((glb_u32*)(const void*)g, (lds_u32*)(void*)l, 16, 0, 0);
}

// 1024 blocks x 512 threads, 1 block/CU (146 KB LDS). Block (xcb, y):
// 128 rows x 208 cols (13 col-frags), K=512 as 4 ksteps of 128 via
// mfma_scale 16x16x128 fp8 (scales=1.0). Ring-3 kstep slots, prefetch
// depth 2, uniform 6 gl16/wave/kstep, vmcnt(6) steady / vmcnt(0) once.
// Col-frag f -> wave wn=f%4 (4/3/3/3: SIMD-balanced). setprio around MFMA.
__global__ __launch_bounds__(512, 2) void sim_kernel(const unsigned char* __restrict__ tl8,
                                                     const unsigned char* __restrict__ ve8,
                                                     const int* __restrict__ mask,
                                                     float* __restrict__ tti) {
  int L = blockIdx.x;
  int xcd = L & 7;
  int idx = L >> 3;              // 0..127
  int y = xcd * 8 + (idx & 7);   // each XCD owns 8 consecutive y's
  int xcb = idx >> 3;            // 0..15 : 4 batch-x per block

  int tid = threadIdx.x;
  int w = tid >> 6, lane = tid & 63;
  int wm = w >> 2;               // 0..1 : rows wm*64..+64 (4 frags)
  int wn = w & 3;                // col frags wn, wn+4, wn+8 (+12 if wn==0)

  __shared__ __attribute__((aligned(16))) unsigned char As[3][8 * 2048];   // 48KB
  __shared__ __attribute__((aligned(16))) unsigned char Bs[3][16 * 2048];  // 96KB
  __shared__ float smax[4 * 128];                                          // 2KB

  const unsigned char* Abase =
      tl8 + (size_t)(xcb >> 1) * GRP_STRIDE + (size_t)(xcb & 1) * 8 * 2048;
  const unsigned char* Bbase = ve8 + (size_t)y * GRP_STRIDE;

  // 48 gl16 units per kstep: 0..15 = A (fa_rel=u>>1, h=u&1), 16..47 = B.
#define STG(s_) do {                                                          \
    int slot_ = (s_) % 3;                                                     \
    _Pragma("unroll")                                                         \
    for (int r_ = 0; r_ < 6; ++r_) {                                          \
      int g_ = w * 6 + r_;                                                    \
      if (g_ < 16) {                                                          \
        int fa_ = g_ >> 1, h_ = g_ & 1;                                       \
        const unsigned char* src_ =                                           \
            Abase + (size_t)(s_) * KS_STRIDE + fa_ * 2048 + h_ * 1024 + lane * 16; \
        gl16(src_, &As[slot_][(fa_ * 2 + h_) * 1024 + lane * 16]);            \
      } else {                                                                \
        int gb_ = g_ - 16;                                                    \
        int fb_ = gb_ >> 1, h_ = gb_ & 1;                                     \
        const unsigned char* src_ =                                           \
            Bbase + (size_t)(s_) * KS_STRIDE + fb_ * 2048 + h_ * 1024 + lane * 16; \
        gl16(src_, &Bs[slot_][(fb_ * 2 + h_) * 1024 + lane * 16]);            \
      }                                                                       \
    }                                                                         \
  } while (0)

#define KCOMPUTE(slot_, NF_) do {                                             \
    i32x8 aop_[4];                                                            \
    _Pragma("unroll")                                                         \
    for (int ma_ = 0; ma_ < 4; ++ma_) {                                       \
      i32x4 h0_ = *(const i32x4*)&As[slot_][((wm * 4 + ma_) * 2) * 1024 + lane * 16]; \
      i32x4 h1_ = *(const i32x4*)&As[slot_][((wm * 4 + ma_) * 2 + 1) * 1024 + lane * 16]; \
      aop_[ma_] = __builtin_shufflevector(h0_, h1_, 0, 1, 2, 3, 4, 5, 6, 7);  \
    }                                                                         \
    i32x8 bop_[NF_];                                                          \
    _Pragma("unroll")                                                         \
    for (int nb_ = 0; nb_ < NF_; ++nb_) {                                     \
      int fb_ = wn + 4 * nb_;                                                 \
      i32x4 h0_ = *(const i32x4*)&Bs[slot_][(fb_ * 2) * 1024 + lane * 16];    \
      i32x4 h1_ = *(const i32x4*)&Bs[slot_][(fb_ * 2 + 1) * 1024 + lane * 16]; \
      bop_[nb_] = __builtin_shufflevector(h0_, h1_, 0, 1, 2, 3, 4, 5, 6, 7);  \
    }                                                                         \
    __builtin_amdgcn_s_setprio(1);                                            \
    _Pragma("unroll")                                                         \
    for (int ma_ = 0; ma_ < 4; ++ma_)                                         \
      _Pragma("unroll")                                                       \
      for (int nb_ = 0; nb_ < NF_; ++nb_)                                     \
        acc[ma_][nb_] = __builtin_amdgcn_mfma_scale_f32_16x16x128_f8f6f4(     \
            aop_[ma_], bop_[nb_], acc[ma_][nb_], 0, 0,                        \
            0, 0x7F7F7F7F, 0, 0x7F7F7F7F);                                    \
    __builtin_amdgcn_s_setprio(0);                                            \
  } while (0)

  f32x4 acc[4][4] = {};

  STG(0); STG(1);
  asm volatile("s_waitcnt vmcnt(6)" ::: "memory");
  __builtin_amdgcn_s_barrier();

  // s=0
  STG(2);
  if (wn == 0) KCOMPUTE(0, 4); else KCOMPUTE(0, 3);
  asm volatile("s_waitcnt vmcnt(6)" ::: "memory");
  __builtin_amdgcn_s_barrier();
  // s=1
  STG(3);
  if (wn == 0) KCOMPUTE(1, 4); else KCOMPUTE(1, 3);
  asm volatile("s_waitcnt vmcnt(6)" ::: "memory");
  __builtin_amdgcn_s_barrier();
  // s=2
  if (wn == 0) KCOMPUTE(2, 4); else KCOMPUTE(2, 3);
  asm volatile("s_waitcnt vmcnt(0)" ::: "memory");
  __builtin_amdgcn_s_barrier();
  // s=3
  if (wn == 0) KCOMPUTE(0, 4); else KCOMPUTE(0, 3);
#undef STG
#undef KCOMPUTE

  // ---- fused epilogue: max over i (i<197), masked mean over t -> tti ----
  int col = lane & 15, gq = lane >> 4;
  int nfrag = (wn == 0) ? 4 : 3;
  bool valid[4];
#pragma unroll
  for (int nb = 0; nb < 4; ++nb) {
    int fb = wn + 4 * nb;
    valid[nb] = (nb < nfrag) && (fb * 16 + col < II);
  }

  float mx[4][4];
#pragma unroll
  for (int ma = 0; ma < 4; ++ma)
#pragma unroll
    for (int reg = 0; reg < 4; ++reg) {
      float m = -FLT_MAX;
#pragma unroll
      for (int nb = 0; nb < 4; ++nb)
        if (valid[nb]) m = fmaxf(m, acc[ma][nb][reg]);
      mx[ma][reg] = m;
    }
#pragma unroll
  for (int st = 1; st <= 8; st <<= 1)
#pragma unroll
    for (int ma = 0; ma < 4; ++ma)
#pragma unroll
      for (int reg = 0; reg < 4; ++reg)
        mx[ma][reg] = fmaxf(mx[ma][reg], __shfl_xor(mx[ma][reg], st));

  if (col == 0) {
#pragma unroll
    for (int ma = 0; ma < 4; ++ma)
#pragma unroll
      for (int reg = 0; reg < 4; ++reg)
        smax[wn * 128 + wm * 64 + ma * 16 + gq * 4 + reg] = mx[ma][reg];
  }
  __syncthreads();

  if (tid < 128) {
    int r = tid;                       // row = x_local*32 + t
    float m = fmaxf(fmaxf(smax[r], smax[128 + r]),
                    fmaxf(smax[256 + r], smax[384 + r]));
    int x = xcb * 4 + (r >> 5), tt = r & 31;
    int mk = mask[x * T1 + 1 + tt];
    float num = mk ? m * TEMP : 0.f;
    float cnt = mk ? 1.f : 0.f;
#pragma unroll
    for (int st = 1; st < 32; st <<= 1) {
      num += __shfl_xor(num, st);
      cnt += __shfl_xor(cnt, st);
    }
    if (tt == 0) tti[x * 64 + y] = num / fmaxf(cnt, 1e-6f);
  }
}

// 1 block x 1024 threads: 16 threads per row x, each sums 4 y's.
__global__ void loss_kernel(const float* __restrict__ tti, float* __restrict__ out) {
  __shared__ float lxs[64];
  int tid = threadIdx.x;
  int x = tid >> 4, q = tid & 15;
  float4 v = *(const float4*)&tti[x * 64 + q * 4];
  float den = expf(v.x) + expf(v.y) + expf(v.z) + expf(v.w);
#pragma unroll
  for (int st = 1; st < 16; st <<= 1) den += __shfl_xor(den, st);
  if (q == 0) {
    float pos = expf(tti[x * 64 + x]);
    lxs[x] = -logf(pos / den + 1e-20f);
  }
  __syncthreads();
  if (tid < 64) {
    float lx = lxs[tid];
#pragma unroll
    for (int s = 1; s < 64; s <<= 1) lx += __shfl_xor(lx, s);
    if (tid == 0) out[0] = lx * (1.0f / 64.0f);
  }
}

extern "C" void kernel_launch(void* const* d_in, const int* in_sizes, int n_in,
                              void* d_out, int out_size, void* d_ws, size_t ws_size,
                              hipStream_t stream) {
  const float* text = (const float*)d_in[0];   // [64][33][512] f32
  const float* video = (const float*)d_in[1];  // [64][197][512] f32
  const int* mask = (const int*)d_in[2];       // [64][33] i32
  float* out = (float*)d_out;

  char* ws = (char*)d_ws;
  unsigned char* tl8 = (unsigned char*)(ws + TL_OFF);
  unsigned char* ve8 = (unsigned char*)(ws + VE_OFF);
  float* tti = (float*)(ws + TTI_OFF);

  hipLaunchKernelGGL(norm_all_kernel, dim3(BB, 8), dim3(256), 0, stream, text, video, tl8, ve8);
  hipLaunchKernelGGL(sim_kernel, dim3(1024), dim3(512), 0, stream, tl8, ve8, mask, tti);
  hipLaunchKernelGGL(loss_kernel, dim3(1), dim3(1024), 0, stream, tti, out);
}